// Round 10
// baseline (281.790 us; speedup 1.0000x reference)
//
#include <hip/hip_runtime.h>

typedef unsigned short u16;
typedef __bf16 bf16x8 __attribute__((ext_vector_type(8)));
typedef float f32x4 __attribute__((ext_vector_type(4)));
typedef float f32x16 __attribute__((ext_vector_type(16)));
typedef unsigned u32x4 __attribute__((ext_vector_type(4)));

#define T_   2048
#define C_   2048
#define HD_  128
#define NH_  16
#define NKV_ 4
#define M_   4096   // B*T

typedef __attribute__((address_space(1))) const void* as1_cvp;
typedef __attribute__((address_space(3))) void* as3_vp;

__device__ __forceinline__ void gload16(const void* g, void* l) {
  __builtin_amdgcn_global_load_lds((as1_cvp)g, (as3_vp)l, 16, 0, 0);
}

__device__ __forceinline__ u16 f2bf(float f) {
  unsigned u = __builtin_bit_cast(unsigned, f);
  return (u16)((u + 0x7fffu + ((u >> 16) & 1u)) >> 16);
}

__device__ __forceinline__ float fexp2(float x) {
  float r;
  asm("v_exp_f32 %0, %1" : "=v"(r) : "v"(x));
  return r;
}

__device__ __forceinline__ unsigned cvtpk(float a, float b) {
  unsigned d;
  asm("v_cvt_pk_bf16_f32 %0, %1, %2" : "=v"(d) : "v"(a), "v"(b));
  return d;
}

// ---------------- fp32 -> bf16 plain convert (x) ----------------
__global__ void cvt_bf16(const float4* __restrict__ in, ushort4* __restrict__ out, int n4) {
  int i = blockIdx.x * blockDim.x + threadIdx.x;
  if (i >= n4) return;
  float4 v = in[i];
  ushort4 r;
  r.x = f2bf(v.x); r.y = f2bf(v.y); r.z = f2bf(v.z); r.w = f2bf(v.w);
  out[i] = r;
}

// ---------------- fused wv + cp convert ----------------
__global__ void cvt_wvcp(const float4* __restrict__ wv, const float4* __restrict__ cp,
                         ushort4* __restrict__ wvb, ushort4* __restrict__ cpb) {
  int i = blockIdx.x * blockDim.x + threadIdx.x;   // 1310720 total
  const float4* src; ushort4* dst; int j;
  if (i < 262144) { src = wv; dst = wvb; j = i; }
  else            { src = cp; dst = cpb; j = i - 262144; }
  float4 v = src[j];
  ushort4 r;
  r.x = f2bf(v.x); r.y = f2bf(v.y); r.z = f2bf(v.z); r.w = f2bf(v.w);
  dst[j] = r;
}

// ---------------- RoPE folded into weight rows (angle indexed by HEAD, per reference quirk) ----
__global__ void rope_fold_w(const float* __restrict__ W, u16* __restrict__ out, int npair) {
  int idx = blockIdx.x * blockDim.x + threadIdx.x;
  int p  = idx >> 9;
  int c4 = (idx & 511) << 2;
  if (p >= npair) return;
  int h  = p >> 6;
  int ii = p & 63;
  float theta = __expf(-(float)ii * (9.210340371976184f / 64.0f));
  float s, c;
  __sincosf((float)h * theta, &s, &c);
  size_t r0 = (size_t)(2 * p) * 2048 + c4;
  size_t r1 = r0 + 2048;
  float4 a = *(const float4*)(W + r0);
  float4 b = *(const float4*)(W + r1);
  ushort4 o0, o1;
  o0.x = f2bf(a.x * c - b.x * s); o0.y = f2bf(a.y * c - b.y * s);
  o0.z = f2bf(a.z * c - b.z * s); o0.w = f2bf(a.w * c - b.w * s);
  o1.x = f2bf(b.x * c + a.x * s); o1.y = f2bf(b.y * c + a.y * s);
  o1.z = f2bf(b.z * c + a.z * s); o1.w = f2bf(b.w * c + a.w * s);
  *(ushort4*)(out + r0) = o0;
  *(ushort4*)(out + r1) = o1;
}

// ---------------- fused bias prep: rope(wq_b), rope(wk_b), copy(wv_b) -> bqkv[3072] -------
__global__ void prep_bias(const float* __restrict__ wq_b, const float* __restrict__ wk_b,
                          const float* __restrict__ wv_b, float* __restrict__ bqkv) {
  int i = blockIdx.x * blockDim.x + threadIdx.x;   // 1536
  if (i < 1280) {
    const float* src = (i < 1024) ? wq_b : wk_b;
    float* dst = (i < 1024) ? bqkv : (bqkv + 2048);
    int p = (i < 1024) ? i : (i - 1024);
    int ii = p & 63;
    float theta = __expf(-(float)ii * (9.210340371976184f / 64.0f));
    float s, c;
    __sincosf((float)(p >> 6) * theta, &s, &c);
    float a = src[2 * p], b = src[2 * p + 1];
    dst[2 * p]     = a * c - b * s;
    dst[2 * p + 1] = b * c + a * s;
  } else if (i < 1536) {
    int p = i - 1280;                               // 256 threads x 2 elems
    bqkv[2560 + 2 * p]     = wv_b[2 * p];
    bqkv[2560 + 2 * p + 1] = wv_b[2 * p + 1];
  }
}

// ---------------- A-in-registers GEMM: C[M,N] = A[M,2048] @ W[N,2048]^T + bias ------------
// BM=128, BK=64, 256 threads = 4 waves as 2M x 2N (wave tile 64 x BN/2). A-fragments are
// loaded DIRECTLY global->VGPR per lane (no LDS round-trip; A-strip private to 2 waves),
// double-buffered in registers. Only B goes through LDS (double-buffered, gload16, slot
// swizzle phys = logical ^ (row&7) via inverse-swizzled source — measured 0 conflicts).
// This halves LDS-port traffic (the measured 30%-MfmaUtil wall) and, with only 24/16 KB
// LDS + ~230 VGPR, 2 blocks co-reside per CU so independent blocks overlap barrier stalls.
// One raw s_barrier per K-step; vmcnt(8) retires exactly B(s+1), A(s+1) stays in flight.
// MODE 0: fused QKV epilogue (BN=192); MODE 1: fp32 [M,2048] out (BN=128).
template<int BN, int MODE>
__global__ __launch_bounds__(256)
void gemm13(const u16* __restrict__ A, const u16* __restrict__ W,
            const float* __restrict__ bias, void* __restrict__ op0,
            void* __restrict__ op1, void* __restrict__ op2, const float qscale) {
  constexpr int NREP = BN / 32;            // n-frags per wave (6 or 4)
  constexpr int BBUF = BN * 64;            // u16 per B K-step buffer
  constexpr int NBL  = BN / 32;            // B stage-loads per thread per K-step (6 or 4)
  __shared__ __align__(16) u16 sm[2 * BBUF];
  const int tid  = threadIdx.x;
  const int lane = tid & 63;
  const int wid  = tid >> 6;
  const int wr = wid >> 1, wc = wid & 1;   // 2M x 2N
  const int m0 = blockIdx.y << 7;
  const int n0 = blockIdx.x * BN;
  const int K  = C_;
  const int fr = lane & 15, g = lane >> 4;
  const int rs0 = ((g ^ (fr & 7)) << 3);         // kh0 swizzled 16B-slot offset (u16)
  const int rs1 = (((4 + g) ^ (fr & 7)) << 3);   // kh1

  // B staging: linear LDS dest, inverse-swizzled global source
  const u16* srcB[NBL]; int dstB[NBL];
#pragma unroll
  for (int l = 0; l < NBL; ++l) {
    const int j = l * 256 + tid, row = j >> 3, sl = j & 7;
    srcB[l] = W + (size_t)(n0 + row) * K + ((sl ^ (row & 7)) << 3);
    dstB[l] = j * 8;
  }
  // A fragment row pointers (per-lane direct loads)
  const u16* ap[4];
#pragma unroll
  for (int mi = 0; mi < 4; ++mi)
    ap[mi] = A + (size_t)(m0 + wr * 64 + mi * 16 + fr) * K + g * 8;

  f32x4 acc[4][NREP] = {};
  bf16x8 afA[4][2], afB[4][2];

  // prologue: stage B(0) (6/4 loads), load A(0) frags (8 loads); vmcnt(8) retires B(0)
#pragma unroll
  for (int l = 0; l < NBL; ++l) gload16(srcB[l], sm + dstB[l]);
#pragma unroll
  for (int mi = 0; mi < 4; ++mi)
#pragma unroll
    for (int kh = 0; kh < 2; ++kh)
      afA[mi][kh] = *(const bf16x8*)(ap[mi] + kh * 32);
  asm volatile("s_waitcnt vmcnt(8)" ::: "memory");
  __builtin_amdgcn_s_barrier();
  __builtin_amdgcn_sched_barrier(0);

#define STEP(s, afC, afN) {                                                   \
    const int bb = ((s) & 1) * BBUF;                                          \
    bf16x8 bq0[NREP], bq1[NREP];                                              \
    _Pragma("unroll")                                                         \
    for (int ni = 0; ni < NREP; ++ni) {                                       \
      const int row = wc * (BN / 2) + ni * 16 + fr;                           \
      bq0[ni] = *(const bf16x8*)&sm[bb + row * 64 + rs0];                     \
      bq1[ni] = *(const bf16x8*)&sm[bb + row * 64 + rs1];                     \
    }                                                                         \
    if ((s) < 31) {                                                           \
      _Pragma("unroll")                                                       \
      for (int l = 0; l < NBL; ++l)                                           \
        gload16(srcB[l] + ((s) + 1) * 64, sm + (((s) & 1) ^ 1) * BBUF + dstB[l]); \
      _Pragma("unroll")                                                       \
      for (int mi = 0; mi < 4; ++mi)                                          \
        _Pragma("unroll")                                                     \
        for (int kh = 0; kh < 2; ++kh)                                        \
          afN[mi][kh] = *(const bf16x8*)(ap[mi] + ((s) + 1) * 64 + kh * 32);  \
    }                                                                         \
    __builtin_amdgcn_s_setprio(1);                                            \
    _Pragma("unroll")                                                         \
    for (int mi = 0; mi < 4; ++mi)                                            \
      _Pragma("unroll")                                                       \
      for (int ni = 0; ni < NREP; ++ni)                                       \
        acc[mi][ni] = __builtin_amdgcn_mfma_f32_16x16x32_bf16(                \
            afC[mi][0], bq0[ni], acc[mi][ni], 0, 0, 0);                       \
    _Pragma("unroll")                                                         \
    for (int mi = 0; mi < 4; ++mi)                                            \
      _Pragma("unroll")                                                       \
      for (int ni = 0; ni < NREP; ++ni)                                       \
        acc[mi][ni] = __builtin_amdgcn_mfma_f32_16x16x32_bf16(                \
            afC[mi][1], bq1[ni], acc[mi][ni], 0, 0, 0);                       \
    __builtin_amdgcn_s_setprio(0);                                            \
    if ((s) < 31) {                                                           \
      asm volatile("s_waitcnt vmcnt(8)" ::: "memory");                        \
      __builtin_amdgcn_s_barrier();                                           \
      __builtin_amdgcn_sched_barrier(0);                                      \
    }                                                                         \
  }

#pragma unroll 1
  for (int sp = 0; sp < 16; ++sp) {
    STEP(2 * sp,     afA, afB)
    STEP(2 * sp + 1, afB, afA)
  }
#undef STEP

  // ---- epilogue
#pragma unroll
  for (int mi = 0; mi < 4; ++mi) {
    const int rg0 = m0 + wr * 64 + mi * 16 + ((lane >> 4) << 2);
#pragma unroll
    for (int ni = 0; ni < NREP; ++ni) {
      const int cg = n0 + wc * (BN / 2) + ni * 16 + fr;
      const float bb2 = bias[cg];
#pragma unroll
      for (int r = 0; r < 4; ++r) {
        float v = acc[mi][ni][r] + bb2;
        const int rg = rg0 + r;
        if (MODE == 1) {
          ((float*)op0)[(size_t)rg * C_ + cg] = v;
        } else {
          const int b = rg >> 11, t = rg & (T_ - 1);
          if (cg < 2048) {
            const int h = cg >> 7, d = cg & 127;
            ((u16*)op0)[((((size_t)b * NH_ + h) * T_ + t) << 7) + d] = f2bf(v * qscale);
          } else if (cg < 2560) {
            const int c2 = cg - 2048, h = c2 >> 7, d = c2 & 127;
            ((u16*)op1)[((((size_t)b * NKV_ + h) * T_ + t) << 7) + d] = f2bf(v);
          } else {
            const int c2 = cg - 2560, h = c2 >> 7, d = c2 & 127;
            ((u16*)op2)[(((size_t)b * NKV_ + h) * HD_ + d) * T_ + t] = f2bf(v);
          }
        }
      }
    }
  }
}

// ---------------- causal GQA flash attention (4 warps x 32 q-rows, 32x32x16 MFMA) ------------
__device__ __forceinline__ void stage_kv(u16* dst, const u16* __restrict__ kg,
                                         const u16* __restrict__ vg, int lane, int w) {
#pragma unroll
  for (int r = 0; r < 4; ++r) {           // K: 64 rows x 16 chunks
    const int row = r * 16 + w * 4 + (lane >> 4);
    const int cg  = (lane & 15) ^ (row & 7);
    gload16(kg + (size_t)row * 128 + cg * 8, dst + row * 128 + (lane & 15) * 8);
  }
#pragma unroll
  for (int r = 0; r < 4; ++r) {           // Vt: 128 rows x 8 chunks
    const int row = r * 32 + w * 8 + (lane >> 3);
    const int cg  = (lane & 7) ^ (row & 7);
    gload16(vg + (size_t)row * T_ + cg * 8, dst + 8192 + row * 64 + (lane & 7) * 8);
  }
}

__global__ __launch_bounds__(256, 2)
void attn2(const u16* __restrict__ q, const u16* __restrict__ k,
           const u16* __restrict__ vt, u16* __restrict__ y) {
  __shared__ __align__(16) u16 sm[32768];
  const int tid  = threadIdx.x;
  const int lane = tid & 63;
  const int w    = tid >> 6;
  const int hi   = lane >> 5;
  const int l5   = lane & 31;
  const int h = blockIdx.y;
  const int b = blockIdx.z;
  // complementary pairing: co-resident (x,y,0)/(x,y,1) get qt summing to 15 -> uniform CU load
  const int qt = b ? (int)blockIdx.x : (15 - (int)blockIdx.x);
  const int q0  = qt << 7;
  const int q0w = q0 + w * 32;
  const int nkv = 2 * qt + 2;
  const size_t qbase = (((size_t)b * NH_ + h) * T_ + q0) * HD_;
  const size_t kbase = ((size_t)b * NKV_ + (h >> 2)) * (size_t)T_ * HD_;
  const size_t vbase = ((size_t)b * NKV_ + (h >> 2)) * (size_t)HD_ * T_;

  // ---- stage Q [128][128] (swizzled) into sm[0..16384)
#pragma unroll
  for (int r = 0; r < 8; ++r) {
    const int row = r * 16 + w * 4 + (lane >> 4);
    const int cg  = (lane & 15) ^ (row & 7);
    gload16(q + qbase + (size_t)row * 128 + cg * 8, sm + row * 128 + (lane & 15) * 8);
  }
  __syncthreads();
  bf16x8 qf[8];
  {
    const int row = w * 32 + l5;
#pragma unroll
    for (int kd = 0; kd < 8; ++kd)
      qf[kd] = *(const bf16x8*)&sm[row * 128 + ((((kd << 1) | hi) ^ (row & 7)) << 3)];
  }
  __syncthreads();
  stage_kv(sm, k + kbase, vt + vbase, lane, w);

  f32x16 o[4] = {};
  float m = -1e30f, l = 0.f;

  for (int kv = 0; kv < nkv; ++kv) {
    __syncthreads();               // staging of current buf complete (vmcnt(0)+barrier)
    const int buf = kv & 1;
    if (kv + 1 < nkv)
      stage_kv(sm + ((buf ^ 1) << 14),
               k + kbase + ((size_t)(kv + 1) << 6) * 128,
               vt + vbase + ((kv + 1) << 6), lane, w);

    if ((kv << 6) <= q0w + 31) {
      const u16* Ks = sm + (buf << 14);
      const u16* Vs = Ks + 8192;

      // ---- S^T = K @ Q^T : lane holds S^T[k=crow(r,hi)][q=l5]
      f32x16 st[2] = {};
      __builtin_amdgcn_s_setprio(1);
#pragma unroll
      for (int kt = 0; kt < 2; ++kt) {
        const int krow = kt * 32 + l5;
#pragma unroll
        for (int kd = 0; kd < 8; ++kd) {
          bf16x8 ka = *(const bf16x8*)&Ks[krow * 128 + ((((kd << 1) | hi) ^ (l5 & 7)) << 3)];
          st[kt] = __builtin_amdgcn_mfma_f32_32x32x16_bf16(ka, qf[kd], st[kt], 0, 0, 0);
        }
      }
      __builtin_amdgcn_s_setprio(0);

      // ---- causal mask (diagonal tiles only)
      if ((kv << 6) + 63 > q0w) {
        const int qg = q0w + l5;
#pragma unroll
        for (int kt = 0; kt < 2; ++kt)
#pragma unroll
          for (int r = 0; r < 16; ++r) {
            const int kg = (kv << 6) + kt * 32 + (r & 3) + ((r >> 2) << 3) + (hi << 2);
            if (kg > qg) st[kt][r] = -3.0e38f;
          }
      }

      // ---- online softmax (log2 domain; scale folded into Q)
      float pmax = -3.0e38f;
#pragma unroll
      for (int kt = 0; kt < 2; ++kt)
#pragma unroll
        for (int r = 0; r < 16; ++r) pmax = fmaxf(pmax, st[kt][r]);
      pmax = fmaxf(pmax, __shfl_xor(pmax, 32));
      if (!__all(pmax - m <= 8.0f)) {        // defer-max (T13)
        const float mn = fmaxf(m, pmax);
        const float f = fexp2(m - mn);
        m = mn;
        l *= f;
#pragma unroll
        for (int r = 0; r < 16; ++r) {
          const float fr = __shfl(f, (r & 3) + ((r >> 2) << 3) + (hi << 2));
          o[0][r] *= fr; o[1][r] *= fr; o[2][r] *= fr; o[3][r] *= fr;
        }
      }

      // ---- P = exp2(S^T - m), pack to PV A-fragments in-register, PV MFMAs
      float rs = 0.f;
#pragma unroll
      for (int kt = 0; kt < 2; ++kt) {
#pragma unroll
        for (int s = 0; s < 2; ++s) {
          float e0 = fexp2(st[kt][8 * s + 0] - m), e1 = fexp2(st[kt][8 * s + 1] - m);
          float e2 = fexp2(st[kt][8 * s + 2] - m), e3 = fexp2(st[kt][8 * s + 3] - m);
          float e4 = fexp2(st[kt][8 * s + 4] - m), e5 = fexp2(st[kt][8 * s + 5] - m);
          float e6 = fexp2(st[kt][8 * s + 6] - m), e7 = fexp2(st[kt][8 * s + 7] - m);
          rs += ((e0 + e1) + (e2 + e3)) + ((e4 + e5) + (e6 + e7));
          const unsigned wL0 = cvtpk(e0, e1), wL1 = cvtpk(e2, e3);
          const unsigned wH0 = cvtpk(e4, e5), wH1 = cvtpk(e6, e7);
          const unsigned s0 = hi ? wL0 : wH0, s1 = hi ? wL1 : wH1;
          const unsigned r0 = __shfl_xor(s0, 32), r1 = __shfl_xor(s1, 32);
          u32x4 fw;
          fw.x = hi ? r0 : wL0; fw.y = hi ? r1 : wL1;
          fw.z = hi ? wH0 : r0; fw.w = hi ? wH1 : r1;
          const bf16x8 pa = __builtin_bit_cast(bf16x8, fw);
          const int ch = (((kt * 2 + s) << 1) | hi) ^ (l5 & 7);
          __builtin_amdgcn_s_setprio(1);
#pragma unroll
          for (int ds = 0; ds < 4; ++ds) {
            const int vrow = ds * 32 + l5;
            bf16x8 vb = *(const bf16x8*)&Vs[vrow * 64 + (ch << 3)];
            o[ds] = __builtin_amdgcn_mfma_f32_32x32x16_bf16(pa, vb, o[ds], 0, 0, 0);
          }
          __builtin_amdgcn_s_setprio(0);
        }
      }
      rs += __shfl_xor(rs, 32);
      l += rs;
    }
  }

  // ---- epilogue: O /= l, write y[b, q, h*128 + d]
  const float linv = 1.0f / l;
#pragma unroll
  for (int r = 0; r < 16; ++r) {
    const int crow = (r & 3) + ((r >> 2) << 3) + (hi << 2);
    const float lf = __shfl(linv, crow);
    const int qg = q0w + crow;
    const size_t rowoff = (((size_t)(b << 11) + qg) << 11) + (h << 7) + l5;
#pragma unroll
    for (int ds = 0; ds < 4; ++ds)
      y[rowoff + ds * 32] = f2bf(o[ds][r] * lf);
  }
}

// ---------------- launch ----------------
extern "C" void kernel_launch(void* const* d_in, const int* in_sizes, int n_in,
                              void* d_out, int out_size, void* d_ws, size_t ws_size,
                              hipStream_t stream) {
  (void)in_sizes; (void)n_in; (void)out_size; (void)ws_size;
  const float* x    = (const float*)d_in[0];
  const float* wq_w = (const float*)d_in[1];
  const float* wq_b = (const float*)d_in[2];
  const float* wk_w = (const float*)d_in[3];
  const float* wk_b = (const float*)d_in[4];
  const float* wv_w = (const float*)d_in[5];
  const float* wv_b = (const float*)d_in[6];
  const float* cp_w = (const float*)d_in[7];
  const float* cp_b = (const float*)d_in[8];

  char* ws = (char*)d_ws;
  u16* xb  = (u16*)ws;  ws += (size_t)M_ * C_ * 2;        // x bf16; later reused as y
  u16* wqr = (u16*)ws;  ws += (size_t)C_ * C_ * 2;        // rotated wq (rows 0..2047 of Wcat)
  u16* wkr = (u16*)ws;  ws += (size_t)512 * C_ * 2;       // rotated wk (rows 2048..2559)
  u16* wvb = (u16*)ws;  ws += (size_t)512 * C_ * 2;       // wv        (rows 2560..3071)
  u16* cpb = (u16*)ws;  ws += (size_t)C_ * C_ * 2;
  u16* qb  = (u16*)ws;  ws += (size_t)M_ * C_ * 2;
  u16* kb  = (u16*)ws;  ws += (size_t)M_ * 512 * 2;
  u16* vtb = (u16*)ws;  ws += (size_t)M_ * 512 * 2;
  float* bqkv = (float*)ws; ws += 3072 * 4;               // concat bias (fp32)
  u16* yb = xb;

  cvt_bf16<<<8192, 256, 0, stream>>>((const float4*)x, (ushort4*)xb, 2097152);
  cvt_wvcp<<<5120, 256, 0, stream>>>((const float4*)wv_w, (const float4*)cp_w,
                                     (ushort4*)wvb, (ushort4*)cpb);
  rope_fold_w<<<2048, 256, 0, stream>>>(wq_w, wqr, 1024);
  rope_fold_w<<<512,  256, 0, stream>>>(wk_w, wkr, 256);
  prep_bias<<<6, 256, 0, stream>>>(wq_b, wk_b, wv_b, bqkv);

  // Q pre-scaled by log2e / sqrt(HD) so attention softmax runs in exp2 domain
  const float qscale = 0.08838834764831843f * 1.4426950408889634f;
  gemm13<192, 0><<<dim3(16, 32), 256, 0, stream>>>(xb, wqr, bqkv, qb, kb, vtb, qscale);

  attn2<<<dim3(16, 16, 2), 256, 0, stream>>>(qb, kb, vtb, yb);

  gemm13<128, 1><<<dim3(16, 32), 256, 0, stream>>>(yb, cpb, cp_b, (float*)d_out,
                                                   nullptr, nullptr, 1.0f);
}

// Round 11
// 227.633 us; speedup vs baseline: 1.2379x; 1.2379x over previous
//
#include <hip/hip_runtime.h>

typedef unsigned short u16;
typedef __bf16 bf16x8 __attribute__((ext_vector_type(8)));
typedef float f32x4 __attribute__((ext_vector_type(4)));
typedef float f32x16 __attribute__((ext_vector_type(16)));
typedef unsigned u32x4 __attribute__((ext_vector_type(4)));

#define T_   2048
#define C_   2048
#define HD_  128
#define NH_  16
#define NKV_ 4
#define M_   4096   // B*T

typedef __attribute__((address_space(1))) const void* as1_cvp;
typedef __attribute__((address_space(3))) void* as3_vp;

__device__ __forceinline__ void gload16(const void* g, void* l) {
  __builtin_amdgcn_global_load_lds((as1_cvp)g, (as3_vp)l, 16, 0, 0);
}

__device__ __forceinline__ u16 f2bf(float f) {
  unsigned u = __builtin_bit_cast(unsigned, f);
  return (u16)((u + 0x7fffu + ((u >> 16) & 1u)) >> 16);
}

__device__ __forceinline__ float fexp2(float x) {
  float r;
  asm("v_exp_f32 %0, %1" : "=v"(r) : "v"(x));
  return r;
}

__device__ __forceinline__ unsigned cvtpk(float a, float b) {
  unsigned d;
  asm("v_cvt_pk_bf16_f32 %0, %1, %2" : "=v"(d) : "v"(a), "v"(b));
  return d;
}

// ---------------- fp32 -> bf16 plain convert (x) ----------------
__global__ void cvt_bf16(const float4* __restrict__ in, ushort4* __restrict__ out, int n4) {
  int i = blockIdx.x * blockDim.x + threadIdx.x;
  if (i >= n4) return;
  float4 v = in[i];
  ushort4 r;
  r.x = f2bf(v.x); r.y = f2bf(v.y); r.z = f2bf(v.z); r.w = f2bf(v.w);
  out[i] = r;
}

// ---------------- fused wv + cp convert ----------------
__global__ void cvt_wvcp(const float4* __restrict__ wv, const float4* __restrict__ cp,
                         ushort4* __restrict__ wvb, ushort4* __restrict__ cpb) {
  int i = blockIdx.x * blockDim.x + threadIdx.x;
  const float4* src; ushort4* dst; int j;
  if (i < 262144) { src = wv; dst = wvb; j = i; }
  else            { src = cp; dst = cpb; j = i - 262144; }
  float4 v = src[j];
  ushort4 r;
  r.x = f2bf(v.x); r.y = f2bf(v.y); r.z = f2bf(v.z); r.w = f2bf(v.w);
  dst[j] = r;
}

// ---------------- RoPE folded into weight rows (angle indexed by HEAD, per reference quirk) ----
__global__ void rope_fold_w(const float* __restrict__ W, u16* __restrict__ out, int npair) {
  int idx = blockIdx.x * blockDim.x + threadIdx.x;
  int p  = idx >> 9;
  int c4 = (idx & 511) << 2;
  if (p >= npair) return;
  int h  = p >> 6;
  int ii = p & 63;
  float theta = __expf(-(float)ii * (9.210340371976184f / 64.0f));
  float s, c;
  __sincosf((float)h * theta, &s, &c);
  size_t r0 = (size_t)(2 * p) * 2048 + c4;
  size_t r1 = r0 + 2048;
  float4 a = *(const float4*)(W + r0);
  float4 b = *(const float4*)(W + r1);
  ushort4 o0, o1;
  o0.x = f2bf(a.x * c - b.x * s); o0.y = f2bf(a.y * c - b.y * s);
  o0.z = f2bf(a.z * c - b.z * s); o0.w = f2bf(a.w * c - b.w * s);
  o1.x = f2bf(b.x * c + a.x * s); o1.y = f2bf(b.y * c + a.y * s);
  o1.z = f2bf(b.z * c + a.z * s); o1.w = f2bf(b.w * c + a.w * s);
  *(ushort4*)(out + r0) = o0;
  *(ushort4*)(out + r1) = o1;
}

// ---------------- fused bias prep ----------------
__global__ void prep_bias(const float* __restrict__ wq_b, const float* __restrict__ wk_b,
                          const float* __restrict__ wv_b, float* __restrict__ bqkv) {
  int i = blockIdx.x * blockDim.x + threadIdx.x;
  if (i < 1280) {
    const float* src = (i < 1024) ? wq_b : wk_b;
    float* dst = (i < 1024) ? bqkv : (bqkv + 2048);
    int p = (i < 1024) ? i : (i - 1024);
    int ii = p & 63;
    float theta = __expf(-(float)ii * (9.210340371976184f / 64.0f));
    float s, c;
    __sincosf((float)(p >> 6) * theta, &s, &c);
    float a = src[2 * p], b = src[2 * p + 1];
    dst[2 * p]     = a * c - b * s;
    dst[2 * p + 1] = b * c + a * s;
  } else if (i < 1536) {
    int p = i - 1280;
    bqkv[2560 + 2 * p]     = wv_b[2 * p];
    bqkv[2560 + 2 * p + 1] = wv_b[2 * p + 1];
  }
}

// ---------------- m201-style 8-phase GEMM: C[M,N] = A[M,2048] @ W[N,2048]^T + bias --------
// BM=BN=256, BK=64, 512 thr, 8 waves 2M x 4N (wave tile 128x64; acc[8][4] f32x4).
// 4 quadrant-phases per K-tile, read-ahead-by-one-phase (4/8/8/4 ds_reads per phase),
// 1 half-tile (2 gload16/thread) staged per phase. A TRIPLE-buffered (staged 2 tiles
// ahead at P2/P3 -> ~6-phase HBM cover), B double-buffered (staged at P0/P1).
// Counted waits, never 0 until tail: vmcnt(4) at P1 (retires A(j+1) before its ds_read),
// vmcnt(2) at P2 (retires B(j+1) before P3's ds_read). LDS = 3*32K + 2*32K = 160 KB.
// Swizzle: phys 16B-chunk = logical ^ (row&7), inverse-swizzled global src (0 conflicts).
// MODE 0: fused QKV epilogue; MODE 1: fp32 [M,2048] out.
template<int MODE>
__global__ __launch_bounds__(512)
void gemm16(const u16* __restrict__ A, const u16* __restrict__ W,
            const float* __restrict__ bias, void* __restrict__ op0,
            void* __restrict__ op1, void* __restrict__ op2, const float qscale) {
  __shared__ __align__(16) u16 sm[81920];       // A: 3x16384 @0, B: 2x16384 @49152
  const int tid  = threadIdx.x;
  const int lane = tid & 63;
  const int wid  = tid >> 6;
  const int wr = wid >> 2, wc = wid & 3;        // 2M x 4N
  const int m0 = blockIdx.y << 8;
  const int n0 = blockIdx.x << 8;
  const int K  = C_;
  const int fr = lane & 15, g = lane >> 4;
  const int rs0 = ((g ^ (fr & 7)) << 3);        // k-half 0 swizzled chunk offset (u16)
  const int rs1 = rs0 ^ 32;                     // k-half 1 (chunk+4 -> +32 u16)

  // staging: thread covers slots tid (l=0) and 512+tid (l=1); row r = slot>>3,
  // chunk = slot&7; LDS dest linear, global src chunk pre-swizzled (^ (r&7)).
  const int r0g   = tid >> 3;
  const int scol  = (((tid & 7) ^ (r0g & 7)) << 3);
  const u16* gA0 = A + (size_t)(m0 + r0g) * K + scol;
  const u16* gB0 = W + (size_t)(n0 + r0g) * K + scol;
  const int d0 = tid * 8, d1 = tid * 8 + 4096;
  const size_t LQ = (size_t)64 * K;             // 64-row stride (l step)
  const size_t LH = (size_t)128 * K;            // half stride

#define ST_A(H, KS, BUF) {                                                      \
    gload16(gA0 + (H) * LH + (size_t)(KS) * 64,      sm + (BUF) * 16384 + (H) * 8192 + d0); \
    gload16(gA0 + (H) * LH + LQ + (size_t)(KS) * 64, sm + (BUF) * 16384 + (H) * 8192 + d1); }
#define ST_B(H, KS, BUF) {                                                      \
    gload16(gB0 + (H) * LH + (size_t)(KS) * 64,      sm + 49152 + (BUF) * 16384 + (H) * 8192 + d0); \
    gload16(gB0 + (H) * LH + LQ + (size_t)(KS) * 64, sm + 49152 + (BUF) * 16384 + (H) * 8192 + d1); }
#define RD_A(DST, QM, AB) { _Pragma("unroll")                                   \
    for (int mi = 0; mi < 4; ++mi) {                                            \
      const int row = wr * 128 + (QM) * 64 + mi * 16 + fr;                      \
      DST[mi][0] = *(const bf16x8*)&sm[(AB) + row * 64 + rs0];                  \
      DST[mi][1] = *(const bf16x8*)&sm[(AB) + row * 64 + rs1]; } }
#define RD_B(DST, QN, BB) { _Pragma("unroll")                                   \
    for (int ni = 0; ni < 2; ++ni) {                                            \
      const int row = wc * 64 + (QN) * 32 + ni * 16 + fr;                       \
      DST[ni][0] = *(const bf16x8*)&sm[(BB) + row * 64 + rs0];                  \
      DST[ni][1] = *(const bf16x8*)&sm[(BB) + row * 64 + rs1]; } }
#define MM16(QM, QN, AF, BQ) {                                                  \
    __builtin_amdgcn_s_setprio(1);                                              \
    _Pragma("unroll")                                                           \
    for (int mi = 0; mi < 4; ++mi)                                              \
      _Pragma("unroll")                                                         \
      for (int ni = 0; ni < 2; ++ni) {                                          \
        acc[(QM)*4+mi][(QN)*2+ni] = __builtin_amdgcn_mfma_f32_16x16x32_bf16(    \
            AF[mi][0], BQ[ni][0], acc[(QM)*4+mi][(QN)*2+ni], 0, 0, 0);          \
        acc[(QM)*4+mi][(QN)*2+ni] = __builtin_amdgcn_mfma_f32_16x16x32_bf16(    \
            AF[mi][1], BQ[ni][1], acc[(QM)*4+mi][(QN)*2+ni], 0, 0, 0); }        \
    __builtin_amdgcn_s_setprio(0); }
#define BAR  __builtin_amdgcn_s_barrier();
#define LGKM { asm volatile("s_waitcnt lgkmcnt(0)" ::: "memory");               \
               __builtin_amdgcn_sched_barrier(0); }

  f32x4 acc[8][4] = {};
  bf16x8 af0[4][2], af1[4][2], bq0[2][2], bq1[2][2];

  // prologue: B(0), A(0), A(1); vmcnt(4) leaves A(1) in flight (entry invariant)
  ST_B(0, 0, 0) ST_B(1, 0, 0)
  ST_A(0, 0, 0) ST_A(1, 0, 0)
  ST_A(0, 1, 1) ST_A(1, 1, 1)
  asm volatile("s_waitcnt vmcnt(4)" ::: "memory");
  BAR
  __builtin_amdgcn_sched_barrier(0);
  RD_A(af0, 0, 0)                 // A(0) qm0
  RD_B(bq0, 0, 49152)             // B(0) qn0

  int a0 = 0, a1 = 1, a2 = 2;     // A buf of tile j, j+1, j+2
#pragma unroll 1
  for (int j = 0; j < 32; ++j) {
    const int ab  = a0 * 16384;
    const int abn = a1 * 16384;
    const int bb  = 49152 + (j & 1) * 16384;
    const int bbn = 49152 + ((j + 1) & 1) * 16384;
    const int bs  = (j + 1) & 1;
    // ---- P0: read B(j) qn1; stage B(j+1) h0
    RD_B(bq1, 1, bb)
    if (j < 31) ST_B(0, j + 1, bs)
    BAR LGKM
    MM16(0, 0, af0, bq0)
    BAR
    // ---- P1: read A(j) qm1; stage B(j+1) h1; vmcnt(4) retires A(j+1)
    RD_A(af1, 1, ab)
    if (j < 31) {
      ST_B(1, j + 1, bs)
      asm volatile("s_waitcnt vmcnt(4)" ::: "memory");
    }
    BAR LGKM
    MM16(0, 1, af0, bq1)
    BAR
    // ---- P2: read A(j+1) qm0; stage A(j+2) h0; vmcnt(2) retires B(j+1)
    if (j < 31) RD_A(af0, 0, abn)
    if (j < 30) {
      ST_A(0, j + 2, a2)
      asm volatile("s_waitcnt vmcnt(2)" ::: "memory");
    } else if (j == 30) {
      asm volatile("s_waitcnt vmcnt(0)" ::: "memory");
    }
    BAR LGKM
    MM16(1, 0, af1, bq0)
    BAR
    // ---- P3: read B(j+1) qn0; stage A(j+2) h1
    if (j < 31) RD_B(bq0, 0, bbn)
    if (j < 30) ST_A(1, j + 2, a2)
    BAR LGKM
    MM16(1, 1, af1, bq1)
    BAR
    const int t = a0; a0 = a1; a1 = a2; a2 = t;
  }
#undef ST_A
#undef ST_B
#undef RD_A
#undef RD_B
#undef MM16
#undef BAR
#undef LGKM

  // ---- epilogue
#pragma unroll
  for (int mi = 0; mi < 8; ++mi) {
    const int rg0 = m0 + wr * 128 + mi * 16 + ((lane >> 4) << 2);
#pragma unroll
    for (int ni = 0; ni < 4; ++ni) {
      const int cg = n0 + wc * 64 + ni * 16 + fr;
      const float bb2 = bias[cg];
#pragma unroll
      for (int r = 0; r < 4; ++r) {
        float v = acc[mi][ni][r] + bb2;
        const int rg = rg0 + r;
        if (MODE == 1) {
          ((float*)op0)[(size_t)rg * C_ + cg] = v;
        } else {
          const int b = rg >> 11, t = rg & (T_ - 1);
          if (cg < 2048) {
            const int h = cg >> 7, d = cg & 127;
            ((u16*)op0)[((((size_t)b * NH_ + h) * T_ + t) << 7) + d] = f2bf(v * qscale);
          } else if (cg < 2560) {
            const int c2 = cg - 2048, h = c2 >> 7, d = c2 & 127;
            ((u16*)op1)[((((size_t)b * NKV_ + h) * T_ + t) << 7) + d] = f2bf(v);
          } else {
            const int c2 = cg - 2560, h = c2 >> 7, d = c2 & 127;
            ((u16*)op2)[(((size_t)b * NKV_ + h) * HD_ + d) * T_ + t] = f2bf(v);
          }
        }
      }
    }
  }
}

// ---------------- causal GQA flash attention (unchanged round-9 version) ------------
__device__ __forceinline__ void stage_kv(u16* dst, const u16* __restrict__ kg,
                                         const u16* __restrict__ vg, int lane, int w) {
#pragma unroll
  for (int r = 0; r < 4; ++r) {
    const int row = r * 16 + w * 4 + (lane >> 4);
    const int cg  = (lane & 15) ^ (row & 7);
    gload16(kg + (size_t)row * 128 + cg * 8, dst + row * 128 + (lane & 15) * 8);
  }
#pragma unroll
  for (int r = 0; r < 4; ++r) {
    const int row = r * 32 + w * 8 + (lane >> 3);
    const int cg  = (lane & 7) ^ (row & 7);
    gload16(vg + (size_t)row * T_ + cg * 8, dst + 8192 + row * 64 + (lane & 7) * 8);
  }
}

__global__ __launch_bounds__(256, 2)
void attn2(const u16* __restrict__ q, const u16* __restrict__ k,
           const u16* __restrict__ vt, u16* __restrict__ y) {
  __shared__ __align__(16) u16 sm[32768];
  const int tid  = threadIdx.x;
  const int lane = tid & 63;
  const int w    = tid >> 6;
  const int hi   = lane >> 5;
  const int l5   = lane & 31;
  const int h = blockIdx.y;
  const int b = blockIdx.z;
  const int qt = b ? (int)blockIdx.x : (15 - (int)blockIdx.x);
  const int q0  = qt << 7;
  const int q0w = q0 + w * 32;
  const int nkv = 2 * qt + 2;
  const size_t qbase = (((size_t)b * NH_ + h) * T_ + q0) * HD_;
  const size_t kbase = ((size_t)b * NKV_ + (h >> 2)) * (size_t)T_ * HD_;
  const size_t vbase = ((size_t)b * NKV_ + (h >> 2)) * (size_t)HD_ * T_;

#pragma unroll
  for (int r = 0; r < 8; ++r) {
    const int row = r * 16 + w * 4 + (lane >> 4);
    const int cg  = (lane & 15) ^ (row & 7);
    gload16(q + qbase + (size_t)row * 128 + cg * 8, sm + row * 128 + (lane & 15) * 8);
  }
  __syncthreads();
  bf16x8 qf[8];
  {
    const int row = w * 32 + l5;
#pragma unroll
    for (int kd = 0; kd < 8; ++kd)
      qf[kd] = *(const bf16x8*)&sm[row * 128 + ((((kd << 1) | hi) ^ (row & 7)) << 3)];
  }
  __syncthreads();
  stage_kv(sm, k + kbase, vt + vbase, lane, w);

  f32x16 o[4] = {};
  float m = -1e30f, l = 0.f;

  for (int kv = 0; kv < nkv; ++kv) {
    __syncthreads();
    const int buf = kv & 1;
    if (kv + 1 < nkv)
      stage_kv(sm + ((buf ^ 1) << 14),
               k + kbase + ((size_t)(kv + 1) << 6) * 128,
               vt + vbase + ((kv + 1) << 6), lane, w);

    if ((kv << 6) <= q0w + 31) {
      const u16* Ks = sm + (buf << 14);
      const u16* Vs = Ks + 8192;

      f32x16 st[2] = {};
      __builtin_amdgcn_s_setprio(1);
#pragma unroll
      for (int kt = 0; kt < 2; ++kt) {
        const int krow = kt * 32 + l5;
#pragma unroll
        for (int kd = 0; kd < 8; ++kd) {
          bf16x8 ka = *(const bf16x8*)&Ks[krow * 128 + ((((kd << 1) | hi) ^ (l5 & 7)) << 3)];
          st[kt] = __builtin_amdgcn_mfma_f32_32x32x16_bf16(ka, qf[kd], st[kt], 0, 0, 0);
        }
      }
      __builtin_amdgcn_s_setprio(0);

      if ((kv << 6) + 63 > q0w) {
        const int qg = q0w + l5;
#pragma unroll
        for (int kt = 0; kt < 2; ++kt)
#pragma unroll
          for (int r = 0; r < 16; ++r) {
            const int kg = (kv << 6) + kt * 32 + (r & 3) + ((r >> 2) << 3) + (hi << 2);
            if (kg > qg) st[kt][r] = -3.0e38f;
          }
      }

      float pmax = -3.0e38f;
#pragma unroll
      for (int kt = 0; kt < 2; ++kt)
#pragma unroll
        for (int r = 0; r < 16; ++r) pmax = fmaxf(pmax, st[kt][r]);
      pmax = fmaxf(pmax, __shfl_xor(pmax, 32));
      if (!__all(pmax - m <= 8.0f)) {
        const float mn = fmaxf(m, pmax);
        const float f = fexp2(m - mn);
        m = mn;
        l *= f;
#pragma unroll
        for (int r = 0; r < 16; ++r) {
          const float fr = __shfl(f, (r & 3) + ((r >> 2) << 3) + (hi << 2));
          o[0][r] *= fr; o[1][r] *= fr; o[2][r] *= fr; o[3][r] *= fr;
        }
      }

      float rs = 0.f;
#pragma unroll
      for (int kt = 0; kt < 2; ++kt) {
#pragma unroll
        for (int s = 0; s < 2; ++s) {
          float e0 = fexp2(st[kt][8 * s + 0] - m), e1 = fexp2(st[kt][8 * s + 1] - m);
          float e2 = fexp2(st[kt][8 * s + 2] - m), e3 = fexp2(st[kt][8 * s + 3] - m);
          float e4 = fexp2(st[kt][8 * s + 4] - m), e5 = fexp2(st[kt][8 * s + 5] - m);
          float e6 = fexp2(st[kt][8 * s + 6] - m), e7 = fexp2(st[kt][8 * s + 7] - m);
          rs += ((e0 + e1) + (e2 + e3)) + ((e4 + e5) + (e6 + e7));
          const unsigned wL0 = cvtpk(e0, e1), wL1 = cvtpk(e2, e3);
          const unsigned wH0 = cvtpk(e4, e5), wH1 = cvtpk(e6, e7);
          const unsigned s0 = hi ? wL0 : wH0, s1 = hi ? wL1 : wH1;
          const unsigned r0 = __shfl_xor(s0, 32), r1 = __shfl_xor(s1, 32);
          u32x4 fw;
          fw.x = hi ? r0 : wL0; fw.y = hi ? r1 : wL1;
          fw.z = hi ? wH0 : r0; fw.w = hi ? wH1 : r1;
          const bf16x8 pa = __builtin_bit_cast(bf16x8, fw);
          const int ch = (((kt * 2 + s) << 1) | hi) ^ (l5 & 7);
          __builtin_amdgcn_s_setprio(1);
#pragma unroll
          for (int ds = 0; ds < 4; ++ds) {
            const int vrow = ds * 32 + l5;
            bf16x8 vb = *(const bf16x8*)&Vs[vrow * 64 + (ch << 3)];
            o[ds] = __builtin_amdgcn_mfma_f32_32x32x16_bf16(pa, vb, o[ds], 0, 0, 0);
          }
          __builtin_amdgcn_s_setprio(0);
        }
      }
      rs += __shfl_xor(rs, 32);
      l += rs;
    }
  }

  const float linv = 1.0f / l;
#pragma unroll
  for (int r = 0; r < 16; ++r) {
    const int crow = (r & 3) + ((r >> 2) << 3) + (hi << 2);
    const float lf = __shfl(linv, crow);
    const int qg = q0w + crow;
    const size_t rowoff = (((size_t)(b << 11) + qg) << 11) + (h << 7) + l5;
#pragma unroll
    for (int ds = 0; ds < 4; ++ds)
      y[rowoff + ds * 32] = f2bf(o[ds][r] * lf);
  }
}

// ---------------- launch ----------------
extern "C" void kernel_launch(void* const* d_in, const int* in_sizes, int n_in,
                              void* d_out, int out_size, void* d_ws, size_t ws_size,
                              hipStream_t stream) {
  (void)in_sizes; (void)n_in; (void)out_size; (void)ws_size;
  const float* x    = (const float*)d_in[0];
  const float* wq_w = (const float*)d_in[1];
  const float* wq_b = (const float*)d_in[2];
  const float* wk_w = (const float*)d_in[3];
  const float* wk_b = (const float*)d_in[4];
  const float* wv_w = (const float*)d_in[5];
  const float* wv_b = (const float*)d_in[6];
  const float* cp_w = (const float*)d_in[7];
  const float* cp_b = (const float*)d_in[8];

  char* ws = (char*)d_ws;
  u16* xb  = (u16*)ws;  ws += (size_t)M_ * C_ * 2;
  u16* wqr = (u16*)ws;  ws += (size_t)C_ * C_ * 2;
  u16* wkr = (u16*)ws;  ws += (size_t)512 * C_ * 2;
  u16* wvb = (u16*)ws;  ws += (size_t)512 * C_ * 2;
  u16* cpb = (u16*)ws;  ws += (size_t)C_ * C_ * 2;
  u16* qb  = (u16*)ws;  ws += (size_t)M_ * C_ * 2;
  u16* kb  = (u16*)ws;  ws += (size_t)M_ * 512 * 2;
  u16* vtb = (u16*)ws;  ws += (size_t)M_ * 512 * 2;
  float* bqkv = (float*)ws; ws += 3072 * 4;
  u16* yb = xb;

  cvt_bf16<<<8192, 256, 0, stream>>>((const float4*)x, (ushort4*)xb, 2097152);
  cvt_wvcp<<<5120, 256, 0, stream>>>((const float4*)wv_w, (const float4*)cp_w,
                                     (ushort4*)wvb, (ushort4*)cpb);
  rope_fold_w<<<2048, 256, 0, stream>>>(wq_w, wqr, 1024);
  rope_fold_w<<<512,  256, 0, stream>>>(wk_w, wkr, 256);
  prep_bias<<<6, 256, 0, stream>>>(wq_b, wk_b, wv_b, bqkv);

  const float qscale = 0.08838834764831843f * 1.4426950408889634f;
  gemm16<0><<<dim3(12, 16), 512, 0, stream>>>(xb, wqr, bqkv, qb, kb, vtb, qscale);

  attn2<<<dim3(16, 16, 2), 256, 0, stream>>>(qb, kb, vtb, yb);

  gemm16<1><<<dim3(8, 16), 512, 0, stream>>>(yb, cpb, cp_b, (float*)d_out,
                                             nullptr, nullptr, 1.0f);
}

// Round 12
// 173.750 us; speedup vs baseline: 1.6218x; 1.3101x over previous
//
#include <hip/hip_runtime.h>

typedef unsigned short u16;
typedef __bf16 bf16x8 __attribute__((ext_vector_type(8)));
typedef float f32x4 __attribute__((ext_vector_type(4)));
typedef float f32x16 __attribute__((ext_vector_type(16)));
typedef unsigned u32x4 __attribute__((ext_vector_type(4)));

#define T_   2048
#define C_   2048
#define HD_  128
#define NH_  16
#define NKV_ 4
#define M_   4096   // B*T

typedef __attribute__((address_space(1))) const void* as1_cvp;
typedef __attribute__((address_space(3))) void* as3_vp;

__device__ __forceinline__ void gload16(const void* g, void* l) {
  __builtin_amdgcn_global_load_lds((as1_cvp)g, (as3_vp)l, 16, 0, 0);
}

__device__ __forceinline__ u16 f2bf(float f) {
  unsigned u = __builtin_bit_cast(unsigned, f);
  return (u16)((u + 0x7fffu + ((u >> 16) & 1u)) >> 16);
}

__device__ __forceinline__ float fexp2(float x) {
  float r;
  asm("v_exp_f32 %0, %1" : "=v"(r) : "v"(x));
  return r;
}

__device__ __forceinline__ unsigned cvtpk(float a, float b) {
  unsigned d;
  asm("v_cvt_pk_bf16_f32 %0, %1, %2" : "=v"(d) : "v"(a), "v"(b));
  return d;
}

// ---------------- fused prep: all fp32->bf16 conversions + RoPE folds + biases, ONE launch ----
__device__ __forceinline__ void cvt4(const float* __restrict__ src, u16* __restrict__ dst, int i) {
  float4 v = ((const float4*)src)[i];
  ushort4 r;
  r.x = f2bf(v.x); r.y = f2bf(v.y); r.z = f2bf(v.z); r.w = f2bf(v.w);
  ((ushort4*)dst)[i] = r;
}

// RoPE fold on weight-row pairs (angle indexed by HEAD, per reference quirk)
__device__ __forceinline__ void rope_item(const float* __restrict__ W, u16* __restrict__ out, int i) {
  const int p  = i >> 9;            // row-pair index
  const int c4 = (i & 511) << 2;    // float column
  const int h  = p >> 6;
  const int ii = p & 63;
  const float theta = __expf(-(float)ii * (9.210340371976184f / 64.0f));
  float s, c;
  __sincosf((float)h * theta, &s, &c);
  const size_t r0 = (size_t)(2 * p) * 2048 + c4;
  const size_t r1 = r0 + 2048;
  float4 a = *(const float4*)(W + r0);
  float4 b = *(const float4*)(W + r1);
  ushort4 o0, o1;
  o0.x = f2bf(a.x * c - b.x * s); o0.y = f2bf(a.y * c - b.y * s);
  o0.z = f2bf(a.z * c - b.z * s); o0.w = f2bf(a.w * c - b.w * s);
  o1.x = f2bf(b.x * c + a.x * s); o1.y = f2bf(b.y * c + a.y * s);
  o1.z = f2bf(b.z * c + a.z * s); o1.w = f2bf(b.w * c + a.w * s);
  *(ushort4*)(out + r0) = o0;
  *(ushort4*)(out + r1) = o1;
}

__global__ void prep_all(const float* __restrict__ x,    const float* __restrict__ wq_w,
                         const float* __restrict__ wk_w, const float* __restrict__ wv_w,
                         const float* __restrict__ cp_w, const float* __restrict__ wq_b,
                         const float* __restrict__ wk_b, const float* __restrict__ wv_b,
                         u16* __restrict__ xb,  u16* __restrict__ wqr, u16* __restrict__ wkr,
                         u16* __restrict__ wvb, u16* __restrict__ cpb, float* __restrict__ bqkv) {
  int i = blockIdx.x * blockDim.x + threadIdx.x;
  if (i < 2097152) { cvt4(x, xb, i); return; }            // x  [4096x2048]
  i -= 2097152;
  if (i < 262144)  { cvt4(wv_w, wvb, i); return; }        // wv [512x2048]
  i -= 262144;
  if (i < 1048576) { cvt4(cp_w, cpb, i); return; }        // cp [2048x2048]
  i -= 1048576;
  if (i < 524288)  { rope_item(wq_w, wqr, i); return; }   // wq rope (1024 pairs x 512)
  i -= 524288;
  if (i < 131072)  { rope_item(wk_w, wkr, i); return; }   // wk rope (256 pairs x 512)
  i -= 131072;
  if (i < 1280) {                                          // rope'd biases
    const float* src = (i < 1024) ? wq_b : wk_b;
    float* dst = (i < 1024) ? bqkv : (bqkv + 2048);
    const int p = (i < 1024) ? i : (i - 1024);
    const int ii = p & 63;
    const float theta = __expf(-(float)ii * (9.210340371976184f / 64.0f));
    float s, c;
    __sincosf((float)(p >> 6) * theta, &s, &c);
    const float a = src[2 * p], b = src[2 * p + 1];
    dst[2 * p]     = a * c - b * s;
    dst[2 * p + 1] = b * c + a * s;
  } else if (i < 1536) {
    const int p = i - 1280;
    bqkv[2560 + 2 * p]     = wv_b[2 * p];
    bqkv[2560 + 2 * p + 1] = wv_b[2 * p + 1];
  }
}

// ---------------- compiler-interleaved GEMM (round-9 known-good): C = A @ W^T + bias ------
// BM=256, K-step 64, 8 waves as 4M x 2N (wave tile 64 x BN/2). A TRIPLE-buffered (staged
// 2 K-steps ahead), B double-buffered (1 ahead); issue order B(s+1) then A(s+2) makes the
// once-per-K-step s_waitcnt vmcnt(4) retire exactly {A(s+1),B(s+1)} while A(s+2) stays in
// flight. ONE s_barrier per K-step; body UNPINNED so the compiler interleaves MFMA with
// counted lgkmcnt and drifting waves overlap the LDS and MFMA pipes.
// Swizzle: phys 16B-slot = logical ^ (row&7) via inverse-swizzled global source (rule 21;
// measured 0 bank conflicts). MODE 0: fused QKV epilogue (BN=192); MODE 1: fp32 out (BN=128).
template<int BN, int MODE>
__global__ __launch_bounds__(512)
void gemm11(const u16* __restrict__ A, const u16* __restrict__ W,
            const float* __restrict__ bias, void* __restrict__ op0,
            void* __restrict__ op1, void* __restrict__ op2, const float qscale) {
  constexpr int NREP = BN / 32;
  constexpr int ABUF = 16384;
  constexpr int BBUF = BN * 64;
  constexpr int NBL  = BN / 64;
  __shared__ __align__(16) u16 sm[3 * ABUF + 2 * BBUF];
  const int tid  = threadIdx.x;
  const int lane = tid & 63;
  const int wid  = tid >> 6;
  const int wr = wid >> 1, wc = wid & 1;
  const int m0 = blockIdx.y << 8;
  const int n0 = blockIdx.x * BN;
  const int K  = C_;
  const int fr = lane & 15, g = lane >> 4;
  const int rs0 = ((g ^ (fr & 7)) << 3);
  const int rs1 = (((4 + g) ^ (fr & 7)) << 3);

  size_t sofA[4]; int sdstA[4];
#pragma unroll
  for (int l = 0; l < 4; ++l) {
    const int j = l * 512 + tid, rl = j >> 3, sl = j & 7;
    sofA[l] = (size_t)rl * K + ((sl ^ (rl & 7)) << 3);
    sdstA[l] = j * 8;
  }
  size_t sofB[NBL]; int sdstB[NBL];
#pragma unroll
  for (int l = 0; l < NBL; ++l) {
    const int j = l * 512 + tid, rl = j >> 3, sl = j & 7;
    sofB[l] = (size_t)rl * K + ((sl ^ (rl & 7)) << 3);
    sdstB[l] = j * 8;
  }
  const u16* Ab = A + (size_t)m0 * K;
  const u16* Bb = W + (size_t)n0 * K;

  f32x4 acc[4][NREP] = {};

#define SA(l, ks, buf) gload16(Ab + (size_t)(ks) * 64 + sofA[l], sm + (buf) * ABUF + sdstA[l]);
#define SB(l, ks, buf) gload16(Bb + (size_t)(ks) * 64 + sofB[l], sm + 3 * ABUF + (buf) * BBUF + sdstB[l]);

  // prologue: B(0), A(0), A(1); vmcnt(4) leaves A(1) in flight
#pragma unroll
  for (int l = 0; l < NBL; ++l) SB(l, 0, 0)
#pragma unroll
  for (int l = 0; l < 4; ++l) SA(l, 0, 0)
#pragma unroll
  for (int l = 0; l < 4; ++l) SA(l, 1, 1)
  asm volatile("s_waitcnt vmcnt(4)" ::: "memory");
  __builtin_amdgcn_s_barrier();
  __builtin_amdgcn_sched_barrier(0);

  int a0 = 0, a2 = 2;
  for (int s = 0; s < 32; ++s) {
    const int ab = a0 * ABUF;
    const int bb = 3 * ABUF + (s & 1) * BBUF;
    const int b1 = (s & 1) ^ 1;
    bf16x8 af0[4], af1[4], bq0[NREP], bq1[NREP];
#pragma unroll
    for (int ni = 0; ni < NREP; ++ni)
      bq0[ni] = *(const bf16x8*)&sm[bb + (wc * (BN / 2) + ni * 16 + fr) * 64 + rs0];
#pragma unroll
    for (int mi = 0; mi < 4; ++mi)
      af0[mi] = *(const bf16x8*)&sm[ab + (wr * 64 + mi * 16 + fr) * 64 + rs0];
#pragma unroll
    for (int ni = 0; ni < NREP; ++ni)
      bq1[ni] = *(const bf16x8*)&sm[bb + (wc * (BN / 2) + ni * 16 + fr) * 64 + rs1];
#pragma unroll
    for (int mi = 0; mi < 4; ++mi)
      af1[mi] = *(const bf16x8*)&sm[ab + (wr * 64 + mi * 16 + fr) * 64 + rs1];
    if (s < 31) {
#pragma unroll
      for (int l = 0; l < NBL; ++l) SB(l, s + 1, b1)
    }
    if (s < 30) {
#pragma unroll
      for (int l = 0; l < 4; ++l) SA(l, s + 2, a2)
    }
    __builtin_amdgcn_s_setprio(1);
#pragma unroll
    for (int mi = 0; mi < 4; ++mi)
#pragma unroll
      for (int ni = 0; ni < NREP; ++ni)
        acc[mi][ni] = __builtin_amdgcn_mfma_f32_16x16x32_bf16(af0[mi], bq0[ni], acc[mi][ni], 0, 0, 0);
#pragma unroll
    for (int mi = 0; mi < 4; ++mi)
#pragma unroll
      for (int ni = 0; ni < NREP; ++ni)
        acc[mi][ni] = __builtin_amdgcn_mfma_f32_16x16x32_bf16(af1[mi], bq1[ni], acc[mi][ni], 0, 0, 0);
    __builtin_amdgcn_s_setprio(0);
    if (s < 30)       asm volatile("s_waitcnt vmcnt(4)" ::: "memory");
    else if (s == 30) asm volatile("s_waitcnt vmcnt(0)" ::: "memory");
    if (s < 31) {
      __builtin_amdgcn_s_barrier();
      __builtin_amdgcn_sched_barrier(0);
    }
    a0 = (a0 == 2) ? 0 : a0 + 1;
    a2 = (a2 == 2) ? 0 : a2 + 1;
  }
#undef SA
#undef SB

#pragma unroll
  for (int mi = 0; mi < 4; ++mi) {
    const int rg0 = m0 + wr * 64 + mi * 16 + ((lane >> 4) << 2);
#pragma unroll
    for (int ni = 0; ni < NREP; ++ni) {
      const int cg = n0 + wc * (BN / 2) + ni * 16 + fr;
      const float bb2 = bias[cg];
#pragma unroll
      for (int r = 0; r < 4; ++r) {
        float v = acc[mi][ni][r] + bb2;
        const int rg = rg0 + r;
        if (MODE == 1) {
          ((float*)op0)[(size_t)rg * C_ + cg] = v;
        } else {
          const int b = rg >> 11, t = rg & (T_ - 1);
          if (cg < 2048) {
            const int h = cg >> 7, d = cg & 127;
            ((u16*)op0)[((((size_t)b * NH_ + h) * T_ + t) << 7) + d] = f2bf(v * qscale);
          } else if (cg < 2560) {
            const int c2 = cg - 2048, h = c2 >> 7, d = c2 & 127;
            ((u16*)op1)[((((size_t)b * NKV_ + h) * T_ + t) << 7) + d] = f2bf(v);
          } else {
            const int c2 = cg - 2560, h = c2 >> 7, d = c2 & 127;
            ((u16*)op2)[(((size_t)b * NKV_ + h) * HD_ + d) * T_ + t] = f2bf(v);
          }
        }
      }
    }
  }
}

// ---------------- causal GQA flash attention (round-9 known-good) ------------
__device__ __forceinline__ void stage_kv(u16* dst, const u16* __restrict__ kg,
                                         const u16* __restrict__ vg, int lane, int w) {
#pragma unroll
  for (int r = 0; r < 4; ++r) {
    const int row = r * 16 + w * 4 + (lane >> 4);
    const int cg  = (lane & 15) ^ (row & 7);
    gload16(kg + (size_t)row * 128 + cg * 8, dst + row * 128 + (lane & 15) * 8);
  }
#pragma unroll
  for (int r = 0; r < 4; ++r) {
    const int row = r * 32 + w * 8 + (lane >> 3);
    const int cg  = (lane & 7) ^ (row & 7);
    gload16(vg + (size_t)row * T_ + cg * 8, dst + 8192 + row * 64 + (lane & 7) * 8);
  }
}

__global__ __launch_bounds__(256, 2)
void attn2(const u16* __restrict__ q, const u16* __restrict__ k,
           const u16* __restrict__ vt, u16* __restrict__ y) {
  __shared__ __align__(16) u16 sm[32768];
  const int tid  = threadIdx.x;
  const int lane = tid & 63;
  const int w    = tid >> 6;
  const int hi   = lane >> 5;
  const int l5   = lane & 31;
  const int h = blockIdx.y;
  const int b = blockIdx.z;
  const int qt = b ? (int)blockIdx.x : (15 - (int)blockIdx.x);
  const int q0  = qt << 7;
  const int q0w = q0 + w * 32;
  const int nkv = 2 * qt + 2;
  const size_t qbase = (((size_t)b * NH_ + h) * T_ + q0) * HD_;
  const size_t kbase = ((size_t)b * NKV_ + (h >> 2)) * (size_t)T_ * HD_;
  const size_t vbase = ((size_t)b * NKV_ + (h >> 2)) * (size_t)HD_ * T_;

#pragma unroll
  for (int r = 0; r < 8; ++r) {
    const int row = r * 16 + w * 4 + (lane >> 4);
    const int cg  = (lane & 15) ^ (row & 7);
    gload16(q + qbase + (size_t)row * 128 + cg * 8, sm + row * 128 + (lane & 15) * 8);
  }
  __syncthreads();
  bf16x8 qf[8];
  {
    const int row = w * 32 + l5;
#pragma unroll
    for (int kd = 0; kd < 8; ++kd)
      qf[kd] = *(const bf16x8*)&sm[row * 128 + ((((kd << 1) | hi) ^ (row & 7)) << 3)];
  }
  __syncthreads();
  stage_kv(sm, k + kbase, vt + vbase, lane, w);

  f32x16 o[4] = {};
  float m = -1e30f, l = 0.f;

  for (int kv = 0; kv < nkv; ++kv) {
    __syncthreads();
    const int buf = kv & 1;
    if (kv + 1 < nkv)
      stage_kv(sm + ((buf ^ 1) << 14),
               k + kbase + ((size_t)(kv + 1) << 6) * 128,
               vt + vbase + ((kv + 1) << 6), lane, w);

    if ((kv << 6) <= q0w + 31) {
      const u16* Ks = sm + (buf << 14);
      const u16* Vs = Ks + 8192;

      f32x16 st[2] = {};
      __builtin_amdgcn_s_setprio(1);
#pragma unroll
      for (int kt = 0; kt < 2; ++kt) {
        const int krow = kt * 32 + l5;
#pragma unroll
        for (int kd = 0; kd < 8; ++kd) {
          bf16x8 ka = *(const bf16x8*)&Ks[krow * 128 + ((((kd << 1) | hi) ^ (l5 & 7)) << 3)];
          st[kt] = __builtin_amdgcn_mfma_f32_32x32x16_bf16(ka, qf[kd], st[kt], 0, 0, 0);
        }
      }
      __builtin_amdgcn_s_setprio(0);

      if ((kv << 6) + 63 > q0w) {
        const int qg = q0w + l5;
#pragma unroll
        for (int kt = 0; kt < 2; ++kt)
#pragma unroll
          for (int r = 0; r < 16; ++r) {
            const int kg = (kv << 6) + kt * 32 + (r & 3) + ((r >> 2) << 3) + (hi << 2);
            if (kg > qg) st[kt][r] = -3.0e38f;
          }
      }

      float pmax = -3.0e38f;
#pragma unroll
      for (int kt = 0; kt < 2; ++kt)
#pragma unroll
        for (int r = 0; r < 16; ++r) pmax = fmaxf(pmax, st[kt][r]);
      pmax = fmaxf(pmax, __shfl_xor(pmax, 32));
      if (!__all(pmax - m <= 8.0f)) {
        const float mn = fmaxf(m, pmax);
        const float f = fexp2(m - mn);
        m = mn;
        l *= f;
#pragma unroll
        for (int r = 0; r < 16; ++r) {
          const float fr = __shfl(f, (r & 3) + ((r >> 2) << 3) + (hi << 2));
          o[0][r] *= fr; o[1][r] *= fr; o[2][r] *= fr; o[3][r] *= fr;
        }
      }

      float rs = 0.f;
#pragma unroll
      for (int kt = 0; kt < 2; ++kt) {
#pragma unroll
        for (int s = 0; s < 2; ++s) {
          float e0 = fexp2(st[kt][8 * s + 0] - m), e1 = fexp2(st[kt][8 * s + 1] - m);
          float e2 = fexp2(st[kt][8 * s + 2] - m), e3 = fexp2(st[kt][8 * s + 3] - m);
          float e4 = fexp2(st[kt][8 * s + 4] - m), e5 = fexp2(st[kt][8 * s + 5] - m);
          float e6 = fexp2(st[kt][8 * s + 6] - m), e7 = fexp2(st[kt][8 * s + 7] - m);
          rs += ((e0 + e1) + (e2 + e3)) + ((e4 + e5) + (e6 + e7));
          const unsigned wL0 = cvtpk(e0, e1), wL1 = cvtpk(e2, e3);
          const unsigned wH0 = cvtpk(e4, e5), wH1 = cvtpk(e6, e7);
          const unsigned s0 = hi ? wL0 : wH0, s1 = hi ? wL1 : wH1;
          const unsigned r0 = __shfl_xor(s0, 32), r1 = __shfl_xor(s1, 32);
          u32x4 fw;
          fw.x = hi ? r0 : wL0; fw.y = hi ? r1 : wL1;
          fw.z = hi ? wH0 : r0; fw.w = hi ? wH1 : r1;
          const bf16x8 pa = __builtin_bit_cast(bf16x8, fw);
          const int ch = (((kt * 2 + s) << 1) | hi) ^ (l5 & 7);
          __builtin_amdgcn_s_setprio(1);
#pragma unroll
          for (int ds = 0; ds < 4; ++ds) {
            const int vrow = ds * 32 + l5;
            bf16x8 vb = *(const bf16x8*)&Vs[vrow * 64 + (ch << 3)];
            o[ds] = __builtin_amdgcn_mfma_f32_32x32x16_bf16(pa, vb, o[ds], 0, 0, 0);
          }
          __builtin_amdgcn_s_setprio(0);
        }
      }
      rs += __shfl_xor(rs, 32);
      l += rs;
    }
  }

  const float linv = 1.0f / l;
#pragma unroll
  for (int r = 0; r < 16; ++r) {
    const int crow = (r & 3) + ((r >> 2) << 3) + (hi << 2);
    const float lf = __shfl(linv, crow);
    const int qg = q0w + crow;
    const size_t rowoff = (((size_t)(b << 11) + qg) << 11) + (h << 7) + l5;
#pragma unroll
    for (int ds = 0; ds < 4; ++ds)
      y[rowoff + ds * 32] = f2bf(o[ds][r] * lf);
  }
}

// ---------------- launch ----------------
extern "C" void kernel_launch(void* const* d_in, const int* in_sizes, int n_in,
                              void* d_out, int out_size, void* d_ws, size_t ws_size,
                              hipStream_t stream) {
  (void)in_sizes; (void)n_in; (void)out_size; (void)ws_size;
  const float* x    = (const float*)d_in[0];
  const float* wq_w = (const float*)d_in[1];
  const float* wq_b = (const float*)d_in[2];
  const float* wk_w = (const float*)d_in[3];
  const float* wk_b = (const float*)d_in[4];
  const float* wv_w = (const float*)d_in[5];
  const float* wv_b = (const float*)d_in[6];
  const float* cp_w = (const float*)d_in[7];
  const float* cp_b = (const float*)d_in[8];

  char* ws = (char*)d_ws;
  u16* xb  = (u16*)ws;  ws += (size_t)M_ * C_ * 2;        // x bf16; later reused as y
  u16* wqr = (u16*)ws;  ws += (size_t)C_ * C_ * 2;        // rotated wq (rows 0..2047 of Wcat)
  u16* wkr = (u16*)ws;  ws += (size_t)512 * C_ * 2;       // rotated wk (rows 2048..2559)
  u16* wvb = (u16*)ws;  ws += (size_t)512 * C_ * 2;       // wv        (rows 2560..3071)
  u16* cpb = (u16*)ws;  ws += (size_t)C_ * C_ * 2;
  u16* qb  = (u16*)ws;  ws += (size_t)M_ * C_ * 2;
  u16* kb  = (u16*)ws;  ws += (size_t)M_ * 512 * 2;
  u16* vtb = (u16*)ws;  ws += (size_t)M_ * 512 * 2;
  float* bqkv = (float*)ws; ws += 3072 * 4;               // concat bias (fp32)
  u16* yb = xb;

  // single fused prep launch: 4,064,768 items = 15878 blocks x 256
  prep_all<<<15878, 256, 0, stream>>>(x, wq_w, wk_w, wv_w, cp_w, wq_b, wk_b, wv_b,
                                      xb, wqr, wkr, wvb, cpb, bqkv);

  // Q pre-scaled by log2e / sqrt(HD) so attention softmax runs in exp2 domain
  const float qscale = 0.08838834764831843f * 1.4426950408889634f;
  gemm11<192, 0><<<dim3(16, 16), 512, 0, stream>>>(xb, wqr, bqkv, qb, kb, vtb, qscale);

  attn2<<<dim3(16, 16, 2), 256, 0, stream>>>(qb, kb, vtb, yb);

  gemm11<128, 1><<<dim3(16, 16), 512, 0, stream>>>(yb, cpb, cp_b, (float*)d_out,
                                                   nullptr, nullptr, 1.0f);
}